// Round 8
// baseline (381.785 us; speedup 1.0000x reference)
//
#include <hip/hip_runtime.h>
#include <hip/hip_bf16.h>
#include <math.h>

#define N_EMBD   1024
#define N_HEAD   16
#define HEAD_DIM 64
#define BATCH    2
#define TSEQ     2048
#define RANK     16
#define LORA_SCALE 2.0f
#define M_TOTAL  (BATCH * TSEQ)   // 4096
#define C3       (3 * N_EMBD)     // 3072

typedef unsigned short ushort_t;
typedef __attribute__((ext_vector_type(8))) short bf16x8;
typedef __attribute__((ext_vector_type(4))) float f32x4;

__device__ __forceinline__ float fake_quant(float x, float scale, float zp) {
    float q = rintf(x / scale + zp);
    q = fminf(fmaxf(q, 0.0f), 255.0f);
    return (q - zp) * scale;
}

__device__ __forceinline__ ushort_t bf16bits(float f) {
    union { __hip_bfloat16 h; ushort_t u; } c;
    c.h = __float2bfloat16(f);
    return c.u;
}

__device__ __forceinline__ float bfraw2f(ushort_t u) {
    union { unsigned int i; float f; } c; c.i = ((unsigned int)u) << 16; return c.f;
}

// ---------------- conversion kernels ----------------
__global__ void cvt_split_kernel(const float* __restrict__ in,
                                 __hip_bfloat16* __restrict__ hi,
                                 __hip_bfloat16* __restrict__ lo, int n4) {
    int i = blockIdx.x * 256 + threadIdx.x;
    if (i >= n4) return;
    float4 v = ((const float4*)in)[i];
    float vs[4] = {v.x, v.y, v.z, v.w};
    #pragma unroll
    for (int k = 0; k < 4; ++k) {
        __hip_bfloat16 h = __float2bfloat16(vs[k]);
        hi[i * 4 + k] = h;
        lo[i * 4 + k] = __float2bfloat16(vs[k] - __bfloat162float(h));
    }
}

__global__ void transpose_split_kernel(const float* __restrict__ in,
                                       __hip_bfloat16* __restrict__ hiT,
                                       __hip_bfloat16* __restrict__ loT,
                                       int R, int C) {
    __shared__ float tl[32][33];
    const int c0 = blockIdx.x * 32, r0 = blockIdx.y * 32;
    const int tx = threadIdx.x & 31, ty = threadIdx.x >> 5;
    for (int i = ty; i < 32; i += 8)
        tl[i][tx] = in[(size_t)(r0 + i) * C + c0 + tx];
    __syncthreads();
    for (int i = ty; i < 32; i += 8) {
        float v = tl[tx][i];
        __hip_bfloat16 h = __float2bfloat16(v);
        size_t o = (size_t)(c0 + i) * R + r0 + tx;
        hiT[o] = h;
        if (loT) loT[o] = __float2bfloat16(v - __bfloat162float(h));
    }
}

// Vb[bh][t][d] -> Vt[bh][d][t]  (bf16 transpose, 64x64 tiles)
__global__ void vtrans_kernel(const ushort_t* __restrict__ Vb,
                              ushort_t* __restrict__ Vt) {
    __shared__ ushort_t tl[64][68];
    const int bh = blockIdx.x & 31, tt = blockIdx.x >> 5;
    const int tid = threadIdx.x;
    {
        const int t = tid >> 2, d0 = (tid & 3) * 16;
        const uint4 u = *(const uint4*)(Vb + ((size_t)bh * TSEQ + tt * 64 + t) * 64 + d0);
        *(uint4*)&tl[t][d0] = u;
        *(uint4*)&tl[t][d0 + 8] = *(const uint4*)(Vb + ((size_t)bh * TSEQ + tt * 64 + t) * 64 + d0 + 8);
    }
    __syncthreads();
    const int d = tid >> 2, t0 = (tid & 3) * 16;
    unsigned int wbuf[8];
    #pragma unroll
    for (int j = 0; j < 8; ++j)
        wbuf[j] = (unsigned int)tl[t0 + 2 * j][d] | ((unsigned int)tl[t0 + 2 * j + 1][d] << 16);
    ushort_t* dst = Vt + ((size_t)bh * 64 + d) * TSEQ + tt * 64 + t0;
    *(uint4*)dst       = make_uint4(wbuf[0], wbuf[1], wbuf[2], wbuf[3]);
    *(uint4*)(dst + 8) = make_uint4(wbuf[4], wbuf[5], wbuf[6], wbuf[7]);
}

// ---------------- LoRA rank-16 projection, 4-way K-split ----------------
__global__ void lora_t_part_kernel(const float* __restrict__ x,
                                   const float* __restrict__ la,
                                   float* __restrict__ tpart, int K) {
    __shared__ float Xs[16][64];
    const int tid = threadIdx.x;
    const int ty = tid >> 4, tx = tid & 15;
    const int row0 = blockIdx.x * 16;
    const int kbase = blockIdx.y * 256;
    float acc = 0.0f;
    for (int k0 = kbase; k0 < kbase + 256; k0 += 64) {
        int rr = tid >> 4, kk = (tid & 15) * 4;
        float4 v = *(const float4*)(x + (size_t)(row0 + rr) * K + k0 + kk);
        Xs[rr][kk] = v.x; Xs[rr][kk + 1] = v.y; Xs[rr][kk + 2] = v.z; Xs[rr][kk + 3] = v.w;
        __syncthreads();
        for (int k = 0; k < 64; ++k)
            acc += Xs[ty][k] * la[(size_t)(k0 + k) * RANK + tx];
        __syncthreads();
    }
    tpart[((size_t)blockIdx.y * M_TOTAL + row0 + ty) * RANK + tx] = acc;
}

__global__ void lora_t_part_bf16_kernel(const ushort_t* __restrict__ x,
                                        const float* __restrict__ la,
                                        float* __restrict__ tpart, int K) {
    __shared__ float Xs[16][64];
    const int tid = threadIdx.x;
    const int ty = tid >> 4, tx = tid & 15;
    const int row0 = blockIdx.x * 16;
    const int kbase = blockIdx.y * 256;
    float acc = 0.0f;
    for (int k0 = kbase; k0 < kbase + 256; k0 += 64) {
        int rr = tid >> 4, kk = (tid & 15) * 4;
        const ushort4 u = *(const ushort4*)(x + (size_t)(row0 + rr) * K + k0 + kk);
        Xs[rr][kk] = bfraw2f(u.x); Xs[rr][kk + 1] = bfraw2f(u.y);
        Xs[rr][kk + 2] = bfraw2f(u.z); Xs[rr][kk + 3] = bfraw2f(u.w);
        __syncthreads();
        for (int k = 0; k < 64; ++k)
            acc += Xs[ty][k] * la[(size_t)(k0 + k) * RANK + tx];
        __syncthreads();
    }
    tpart[((size_t)blockIdx.y * M_TOTAL + row0 + ty) * RANK + tx] = acc;
}

// ---------------- MFMA GEMM (128x128 tile, BK=32, 3 blocks/CU) ----------------
__device__ __forceinline__ int sw_off(int r, int c) {
    return ((r >> 1) << 7) + (((((r & 1) << 2) | c) ^ ((r >> 1) & 7)) << 4);
}

template <bool SPLIT>
__global__ __launch_bounds__(256, 3)
void gemm_mfma_kernel(const __hip_bfloat16* __restrict__ Ah,
                      const __hip_bfloat16* __restrict__ Al,
                      const __hip_bfloat16* __restrict__ Bh,
                      const __hip_bfloat16* __restrict__ Bl,
                      const float* __restrict__ bias,
                      const float* __restrict__ tpart,
                      const float* __restrict__ lb,
                      float* __restrict__ Cf,
                      ushort_t* __restrict__ Qb,
                      ushort_t* __restrict__ Kb,
                      ushort_t* __restrict__ Vb,
                      const float* __restrict__ sp,
                      const float* __restrict__ zp,
                      int M, int N, int K, int split_col0, int out_mode) {
    constexpr int TILE = 128 * 32;              // bf16 elements per 128x32 tile
    __shared__ __hip_bfloat16 As[(SPLIT ? 2 : 1) * TILE];
    __shared__ __hip_bfloat16 Bs[(SPLIT ? 2 : 1) * TILE];
    __shared__ float Ts[128 * 16];
    __shared__ float Ls[16 * 128];

    const int tid = threadIdx.x;
    const int lane = tid & 63, w = tid >> 6;
    const int row0 = blockIdx.y * 128, col0 = blockIdx.x * 128;
    const int wr = (w >> 1) * 64, wc = (w & 1) * 64;
    const bool do_split = SPLIT && (col0 >= split_col0);

    const int s_lc = (lane & 7) ^ ((lane >> 3) & 7);
    const int s_rb = 2 * (lane >> 3) + (s_lc >> 2);
    const int s_c8 = (s_lc & 3) * 8;

    float qsc = 0.f, qzp = 0.f;
    if (out_mode == 1) { qsc = sp[0]; qzp = zp[0]; }

    f32x4 acc[4][4];
    #pragma unroll
    for (int i = 0; i < 4; ++i)
        #pragma unroll
        for (int j = 0; j < 4; ++j)
            acc[i][j] = (f32x4){0.f, 0.f, 0.f, 0.f};

    const int arow = wr + (lane & 15);
    const int chunk = lane >> 4;

    for (int k0 = 0; k0 < K; k0 += 32) {
        #pragma unroll
        for (int qq = 0; qq < 2; ++qq) {
            const int q = 2 * w + qq;          // 16-row group 0..7
            const int r = 16 * q + s_rb;
            const __hip_bfloat16* gA = Ah + (size_t)(row0 + r) * K + k0 + s_c8;
            __builtin_amdgcn_global_load_lds(
                (const __attribute__((address_space(1))) void*)gA,
                (__attribute__((address_space(3))) void*)(As + q * 512), 16, 0, 0);
            const __hip_bfloat16* gB = Bh + (size_t)(col0 + r) * K + k0 + s_c8;
            __builtin_amdgcn_global_load_lds(
                (const __attribute__((address_space(1))) void*)gB,
                (__attribute__((address_space(3))) void*)(Bs + q * 512), 16, 0, 0);
            if (do_split) {
                const __hip_bfloat16* gAl = Al + (size_t)(row0 + r) * K + k0 + s_c8;
                __builtin_amdgcn_global_load_lds(
                    (const __attribute__((address_space(1))) void*)gAl,
                    (__attribute__((address_space(3))) void*)(As + TILE + q * 512), 16, 0, 0);
                const __hip_bfloat16* gBl = Bl + (size_t)(col0 + r) * K + k0 + s_c8;
                __builtin_amdgcn_global_load_lds(
                    (const __attribute__((address_space(1))) void*)gBl,
                    (__attribute__((address_space(3))) void*)(Bs + TILE + q * 512), 16, 0, 0);
            }
        }
        __syncthreads();

        const char* ab = (const char*)As;
        const char* bb = (const char*)Bs;
        bf16x8 a_h[4], b_h[4], a_l[4], b_l[4];
        #pragma unroll
        for (int mi = 0; mi < 4; ++mi) {
            int off = sw_off(arow + mi * 16, chunk);
            a_h[mi] = *(const bf16x8*)(ab + off);
            if (do_split) a_l[mi] = *(const bf16x8*)(ab + 2 * TILE + off);
        }
        #pragma unroll
        for (int nj = 0; nj < 4; ++nj) {
            int off = sw_off(wc + nj * 16 + (lane & 15), chunk);
            b_h[nj] = *(const bf16x8*)(bb + off);
            if (do_split) b_l[nj] = *(const bf16x8*)(bb + 2 * TILE + off);
        }
        #pragma unroll
        for (int mi = 0; mi < 4; ++mi)
            #pragma unroll
            for (int nj = 0; nj < 4; ++nj) {
                acc[mi][nj] = __builtin_amdgcn_mfma_f32_16x16x32_bf16(a_h[mi], b_h[nj], acc[mi][nj], 0, 0, 0);
                if (do_split) {
                    acc[mi][nj] = __builtin_amdgcn_mfma_f32_16x16x32_bf16(a_h[mi], b_l[nj], acc[mi][nj], 0, 0, 0);
                    acc[mi][nj] = __builtin_amdgcn_mfma_f32_16x16x32_bf16(a_l[mi], b_h[nj], acc[mi][nj], 0, 0, 0);
                }
            }
        __syncthreads();
    }

    // ---- epilogue: bias + LORA_SCALE * ((sum of tparts) @ lb) ----
    {
        int r = tid >> 1, j0 = (tid & 1) * 8;
        float4 t0 = {0, 0, 0, 0}, t1 = {0, 0, 0, 0};
        #pragma unroll
        for (int c = 0; c < 4; ++c) {
            const float* src = tpart + ((size_t)c * M_TOTAL + row0 + r) * RANK + j0;
            float4 s0 = *(const float4*)src;
            float4 s1 = *(const float4*)(src + 4);
            t0.x += s0.x; t0.y += s0.y; t0.z += s0.z; t0.w += s0.w;
            t1.x += s1.x; t1.y += s1.y; t1.z += s1.z; t1.w += s1.w;
        }
        *(float4*)(Ts + r * 16 + j0)     = t0;
        *(float4*)(Ts + r * 16 + j0 + 4) = t1;
        int rr = tid >> 4, c0 = (tid & 15) * 8;
        const float4* lsrc = (const float4*)(lb + (size_t)rr * N + col0 + c0);
        float4* ldst = (float4*)(Ls + rr * 128 + c0);
        ldst[0] = lsrc[0]; ldst[1] = lsrc[1];
    }
    __syncthreads();
    #pragma unroll
    for (int mi = 0; mi < 4; ++mi)
        #pragma unroll
        for (int nj = 0; nj < 4; ++nj) {
            const int coll = wc + nj * 16 + (lane & 15);
            const float bv = bias[col0 + coll];
            #pragma unroll
            for (int rg = 0; rg < 4; ++rg) {
                const int rowl = wr + mi * 16 + (lane >> 4) * 4 + rg;
                float lsum = 0.f;
                #pragma unroll
                for (int rr = 0; rr < 16; ++rr)
                    lsum += Ts[rowl * 16 + rr] * Ls[rr * 128 + coll];
                const float val = acc[mi][nj][rg] + bv + LORA_SCALE * lsum;
                if (out_mode == 0) {
                    Cf[(size_t)(row0 + rowl) * N + col0 + coll] = val;
                } else {
                    const int R = row0 + rowl;
                    const int b = R >> 11, t = R & 2047;
                    const int CN = col0 + coll;
                    const int sec = CN >> 10, head = (CN >> 6) & 15, d = CN & 63;
                    const size_t off = (((size_t)(b * 16 + head)) * TSEQ + t) * 64 + d;
                    if (sec == 0)      Qb[off] = bf16bits(val * 0.125f);
                    else if (sec == 1) Kb[off] = bf16bits(fake_quant(val, qsc, qzp));
                    else               Vb[off] = bf16bits(fake_quant(val, qsc, qzp));
                }
            }
        }
}

// ---------------- MFMA flash attention: 128-row Q supertiles ----------------
// 512 blocks = 32 bh x 16 q-supertiles. 4 waves x 32 q-rows (2 x 16-row groups).
// Per 64-key tile: 32 MFMAs/wave between barriers (2x the old ratio); K/V
// global traffic halves. Causal mask via delta = 64*kt - 128*qt2 (uniform).
__global__ __launch_bounds__(256)
void mfma_attn_kernel(const ushort_t* __restrict__ Qb,   // [bh][T][64] (x0.125)
                      const ushort_t* __restrict__ Kq,   // [bh][T][64]
                      const ushort_t* __restrict__ Vtq,  // [bh][64][T]
                      ushort_t* __restrict__ outb) {     // [B][T][1024] bf16
    const int bx = blockIdx.x;
    const int bh = bx & 31;
    const int qt2 = 15 - (bx >> 5);                // heavy supertiles dispatch first
    const int b = bh >> 4, h = bh & 15;
    const int tid = threadIdx.x;
    const int lane = tid & 63, w = tid >> 6;
    const int m16 = lane & 15, qc = lane >> 4;
    const int m7 = m16 & 7;

    __shared__ ushort_t Qs[8192];   // 128 rows x 64
    __shared__ ushort_t Ks[4096];   //  64 rows x 64
    __shared__ ushort_t Vs[4096];   //  64 d    x 64 t
    __shared__ ushort_t Ps[8192];   // 128 rows x 64

    const int s_g = (lane & 7) ^ ((lane >> 3) & 7);
    const int s_r = lane >> 3;

    const ushort_t* Qg = Qb + (size_t)bh * TSEQ * 64;
    const ushort_t* Kg = Kq + (size_t)bh * TSEQ * 64;
    const ushort_t* Vg = Vtq + (size_t)bh * 64 * TSEQ;

    // ---- stage Q supertile once (128 rows) ----
    #pragma unroll
    for (int pp = 0; pp < 4; ++pp) {
        const int p = 4 * w + pp;                  // 0..15, rows 8p..8p+7
        const ushort_t* gq = Qg + ((size_t)(qt2 * 128 + 8 * p + s_r)) * 64 + s_g * 8;
        __builtin_amdgcn_global_load_lds(
            (const __attribute__((address_space(1))) void*)gq,
            (__attribute__((address_space(3))) void*)(Qs + p * 512), 16, 0, 0);
    }
    __syncthreads();

    bf16x8 a_q[2][2];    // [row-group][k-chunk]
    #pragma unroll
    for (int rg = 0; rg < 2; ++rg) {
        const int row = 32 * w + 16 * rg + m16;
        #pragma unroll
        for (int c = 0; c < 2; ++c) {
            const int g = qc + 4 * c;
            a_q[rg][c] = *(const bf16x8*)((const char*)Qs + row * 128 + ((g ^ (row & 7)) << 4));
        }
    }

    float m_st[2][4], l_st[2][4];
    f32x4 o_acc[2][4];
    #pragma unroll
    for (int rg = 0; rg < 2; ++rg)
        #pragma unroll
        for (int r = 0; r < 4; ++r) { m_st[rg][r] = -INFINITY; l_st[rg][r] = 0.0f; }
    #pragma unroll
    for (int rg = 0; rg < 2; ++rg)
        #pragma unroll
        for (int dj = 0; dj < 4; ++dj) o_acc[rg][dj] = (f32x4){0.f, 0.f, 0.f, 0.f};

    const int kt_hi = 2 * qt2 + 1;
    for (int kt = 0; kt <= kt_hi; ++kt) {
        __syncthreads();
        #pragma unroll
        for (int pp = 0; pp < 2; ++pp) {
            const int p = 2 * w + pp;
            const ushort_t* gk = Kg + ((size_t)(kt * 64 + 8 * p + s_r)) * 64 + s_g * 8;
            __builtin_amdgcn_global_load_lds(
                (const __attribute__((address_space(1))) void*)gk,
                (__attribute__((address_space(3))) void*)(Ks + p * 512), 16, 0, 0);
            const ushort_t* gv = Vg + ((size_t)(8 * p + s_r)) * TSEQ + kt * 64 + s_g * 8;
            __builtin_amdgcn_global_load_lds(
                (const __attribute__((address_space(1))) void*)gv,
                (__attribute__((address_space(3))) void*)(Vs + p * 512), 16, 0, 0);
        }
        __syncthreads();

        const int delta = 64 * kt - 128 * qt2;     // key base - query base
        const int kmax0 = 32 * w + 15 - delta;     // max unmasked k, row-group 0
        const int kmax1 = kmax0 + 16;              // row-group 1

        // ---- S = Q @ K^T  (skip fully-masked 16-col groups) ----
        f32x4 s[2][4];
        #pragma unroll
        for (int rg = 0; rg < 2; ++rg)
            #pragma unroll
            for (int nj = 0; nj < 4; ++nj) s[rg][nj] = (f32x4){0.f, 0.f, 0.f, 0.f};
        #pragma unroll
        for (int c = 0; c < 2; ++c) {
            #pragma unroll
            for (int nj = 0; nj < 4; ++nj) {
                if (16 * nj <= kmax1) {
                    const int row = 16 * nj + m16;
                    const int g = qc + 4 * c;
                    bf16x8 bk = *(const bf16x8*)((const char*)Ks + row * 128 + ((g ^ m7) << 4));
                    if (16 * nj <= kmax0)
                        s[0][nj] = __builtin_amdgcn_mfma_f32_16x16x32_bf16(a_q[0][c], bk, s[0][nj], 0, 0, 0);
                    s[1][nj] = __builtin_amdgcn_mfma_f32_16x16x32_bf16(a_q[1][c], bk, s[1][nj], 0, 0, 0);
                }
            }
        }

        // ---- online softmax (mask is pure arithmetic; safe for all tiles) ----
        float alpha[2][4];
        #pragma unroll
        for (int rg = 0; rg < 2; ++rg) {
            #pragma unroll
            for (int reg = 0; reg < 4; ++reg) {
                const int qrow = 32 * w + 16 * rg + 4 * qc + reg;  // local q row
                const int dq = qrow - delta;                        // max unmasked k
                float sv[4];
                float rm = -INFINITY;
                #pragma unroll
                for (int nj = 0; nj < 4; ++nj) {
                    float v = s[rg][nj][reg];
                    if (m16 + 16 * nj > dq) v = -INFINITY;
                    sv[nj] = v;
                    rm = fmaxf(rm, v);
                }
                #pragma unroll
                for (int off = 1; off < 16; off <<= 1)
                    rm = fmaxf(rm, __shfl_xor(rm, off, 16));
                const float mo = m_st[rg][reg];
                const float mn = fmaxf(mo, rm);
                const float al = __expf(mo - mn);
                float rs = 0.f;
                float pv[4];
                #pragma unroll
                for (int nj = 0; nj < 4; ++nj) {
                    pv[nj] = __expf(sv[nj] - mn);
                    rs += pv[nj];
                }
                #pragma unroll
                for (int off = 1; off < 16; off <<= 1)
                    rs += __shfl_xor(rs, off, 16);
                l_st[rg][reg] = al * l_st[rg][reg] + rs;
                m_st[rg][reg] = mn;
                alpha[rg][reg] = al;
                // P -> LDS (bf16, same-wave round trip)
                const int row = qrow;
                const int r7 = row & 7;
                #pragma unroll
                for (int nj = 0; nj < 4; ++nj) {
                    const int k = m16 + 16 * nj;
                    Ps[row * 64 + (((k >> 3) ^ r7) << 3) + (k & 7)] = bf16bits(pv[nj]);
                }
            }
        }

        // ---- rescale O, then O += P @ V (skip all-zero 32-k chunks) ----
        #pragma unroll
        for (int rg = 0; rg < 2; ++rg)
            #pragma unroll
            for (int dj = 0; dj < 4; ++dj)
                #pragma unroll
                for (int reg = 0; reg < 4; ++reg)
                    o_acc[rg][dj][reg] *= alpha[rg][reg];

        #pragma unroll
        for (int c = 0; c < 2; ++c) {
            if (32 * c <= kmax1) {
                const int g = qc + 4 * c;
                bf16x8 ap[2];
                #pragma unroll
                for (int rg = 0; rg < 2; ++rg) {
                    const int rowp = 32 * w + 16 * rg + m16;
                    ap[rg] = *(const bf16x8*)((const char*)Ps + rowp * 128 + ((g ^ m7) << 4));
                }
                #pragma unroll
                for (int dj = 0; dj < 4; ++dj) {
                    const int rowv = 16 * dj + m16;
                    bf16x8 bv = *(const bf16x8*)((const char*)Vs + rowv * 128 + ((g ^ m7) << 4));
                    if (32 * c <= kmax0)
                        o_acc[0][dj] = __builtin_amdgcn_mfma_f32_16x16x32_bf16(ap[0], bv, o_acc[0][dj], 0, 0, 0);
                    o_acc[1][dj] = __builtin_amdgcn_mfma_f32_16x16x32_bf16(ap[1], bv, o_acc[1][dj], 0, 0, 0);
                }
            }
        }
    }

    // ---- epilogue ----
    #pragma unroll
    for (int rg = 0; rg < 2; ++rg)
        #pragma unroll
        for (int reg = 0; reg < 4; ++reg) {
            const float inv = 1.0f / l_st[rg][reg];
            const int q = qt2 * 128 + 32 * w + 16 * rg + 4 * qc + reg;
            #pragma unroll
            for (int dj = 0; dj < 4; ++dj) {
                const int d = m16 + 16 * dj;
                outb[((size_t)b * TSEQ + q) * N_EMBD + h * 64 + d] =
                    bf16bits(o_acc[rg][dj][reg] * inv);
            }
        }
}

extern "C" void kernel_launch(void* const* d_in, const int* in_sizes, int n_in,
                              void* d_out, int out_size, void* d_ws, size_t ws_size,
                              hipStream_t stream) {
    const float* x        = (const float*)d_in[0];
    const float* w_attn   = (const float*)d_in[1];
    const float* b_attn   = (const float*)d_in[2];
    const float* la_attn  = (const float*)d_in[3];
    const float* lb_attn  = (const float*)d_in[4];
    const float* w_proj   = (const float*)d_in[5];
    const float* b_proj   = (const float*)d_in[6];
    const float* la_proj  = (const float*)d_in[7];
    const float* lb_proj  = (const float*)d_in[8];
    const float* kv_scale = (const float*)d_in[9];
    const float* kv_zp    = (const float*)d_in[10];
    float* out = (float*)d_out;

    char* ws = (char*)d_ws;
    float* t_attn_p       = (float*)ws;          ws += (size_t)4 * M_TOTAL * RANK * 4;
    float* t_proj_p       = (float*)ws;          ws += (size_t)4 * M_TOTAL * RANK * 4;
    ushort_t* aob         = (ushort_t*)ws;       ws += (size_t)M_TOTAL * N_EMBD * 2;
    __hip_bfloat16* x_hi  = (__hip_bfloat16*)ws; ws += (size_t)M_TOTAL * N_EMBD * 2;
    __hip_bfloat16* x_lo  = (__hip_bfloat16*)ws; ws += (size_t)M_TOTAL * N_EMBD * 2;
    __hip_bfloat16* wqT_h = (__hip_bfloat16*)ws; ws += (size_t)C3 * N_EMBD * 2;
    __hip_bfloat16* wqT_l = (__hip_bfloat16*)ws; ws += (size_t)C3 * N_EMBD * 2;
    __hip_bfloat16* wpT   = (__hip_bfloat16*)ws; ws += (size_t)N_EMBD * N_EMBD * 2;
    ushort_t* Qb          = (ushort_t*)ws;       ws += (size_t)32 * TSEQ * 64 * 2;
    ushort_t* Kb          = (ushort_t*)ws;       ws += (size_t)32 * TSEQ * 64 * 2;
    ushort_t* Vb          = (ushort_t*)ws;       ws += (size_t)32 * TSEQ * 64 * 2;
    ushort_t* Vtq         = (ushort_t*)ws;       ws += (size_t)32 * 64 * TSEQ * 2;

    cvt_split_kernel<<<dim3(M_TOTAL * N_EMBD / 4 / 256), 256, 0, stream>>>(
        x, x_hi, x_lo, M_TOTAL * N_EMBD / 4);
    transpose_split_kernel<<<dim3(C3 / 32, N_EMBD / 32), 256, 0, stream>>>(
        w_attn, wqT_h, wqT_l, N_EMBD, C3);
    transpose_split_kernel<<<dim3(N_EMBD / 32, N_EMBD / 32), 256, 0, stream>>>(
        w_proj, wpT, nullptr, N_EMBD, N_EMBD);
    lora_t_part_kernel<<<dim3(M_TOTAL / 16, 4), 256, 0, stream>>>(x, la_attn, t_attn_p, N_EMBD);

    // split only V columns (col0 >= 2048) — round-5-validated numerics.
    gemm_mfma_kernel<true><<<dim3(C3 / 128, M_TOTAL / 128), 256, 0, stream>>>(
        x_hi, x_lo, wqT_h, wqT_l, b_attn, t_attn_p, lb_attn,
        nullptr, Qb, Kb, Vb, kv_scale, kv_zp,
        M_TOTAL, C3, N_EMBD, 2 * N_EMBD, 1);

    vtrans_kernel<<<dim3(32 * (TSEQ / 64)), 256, 0, stream>>>(Vb, Vtq);

    mfma_attn_kernel<<<dim3(32 * 16), 256, 0, stream>>>(Qb, Kb, Vtq, aob);

    lora_t_part_bf16_kernel<<<dim3(M_TOTAL / 16, 4), 256, 0, stream>>>(aob, la_proj, t_proj_p, N_EMBD);

    gemm_mfma_kernel<false><<<dim3(N_EMBD / 128, M_TOTAL / 128), 256, 0, stream>>>(
        (const __hip_bfloat16*)aob, nullptr, wpT, nullptr, b_proj, t_proj_p, lb_proj,
        out, nullptr, nullptr, nullptr, nullptr, nullptr,
        M_TOTAL, N_EMBD, N_EMBD, 1 << 30, 0);
}

// Round 9
// 347.526 us; speedup vs baseline: 1.0986x; 1.0986x over previous
//
#include <hip/hip_runtime.h>
#include <hip/hip_bf16.h>
#include <math.h>

#define N_EMBD   1024
#define N_HEAD   16
#define HEAD_DIM 64
#define BATCH    2
#define TSEQ     2048
#define RANK     16
#define LORA_SCALE 2.0f
#define M_TOTAL  (BATCH * TSEQ)   // 4096
#define C3       (3 * N_EMBD)     // 3072

typedef unsigned short ushort_t;
typedef __attribute__((ext_vector_type(8))) short bf16x8;
typedef __attribute__((ext_vector_type(4))) float f32x4;

__device__ __forceinline__ float fake_quant(float x, float scale, float zp) {
    float q = rintf(x / scale + zp);
    q = fminf(fmaxf(q, 0.0f), 255.0f);
    return (q - zp) * scale;
}

__device__ __forceinline__ ushort_t bf16bits(float f) {
    union { __hip_bfloat16 h; ushort_t u; } c;
    c.h = __float2bfloat16(f);
    return c.u;
}

__device__ __forceinline__ float bfraw2f(ushort_t u) {
    union { unsigned int i; float f; } c; c.i = ((unsigned int)u) << 16; return c.f;
}

// ---------------- conversion kernels ----------------
__global__ void cvt_split_kernel(const float* __restrict__ in,
                                 __hip_bfloat16* __restrict__ hi,
                                 __hip_bfloat16* __restrict__ lo, int n4) {
    int i = blockIdx.x * 256 + threadIdx.x;
    if (i >= n4) return;
    float4 v = ((const float4*)in)[i];
    float vs[4] = {v.x, v.y, v.z, v.w};
    #pragma unroll
    for (int k = 0; k < 4; ++k) {
        __hip_bfloat16 h = __float2bfloat16(vs[k]);
        hi[i * 4 + k] = h;
        lo[i * 4 + k] = __float2bfloat16(vs[k] - __bfloat162float(h));
    }
}

__global__ void transpose_split_kernel(const float* __restrict__ in,
                                       __hip_bfloat16* __restrict__ hiT,
                                       __hip_bfloat16* __restrict__ loT,
                                       int R, int C) {
    __shared__ float tl[32][33];
    const int c0 = blockIdx.x * 32, r0 = blockIdx.y * 32;
    const int tx = threadIdx.x & 31, ty = threadIdx.x >> 5;
    for (int i = ty; i < 32; i += 8)
        tl[i][tx] = in[(size_t)(r0 + i) * C + c0 + tx];
    __syncthreads();
    for (int i = ty; i < 32; i += 8) {
        float v = tl[tx][i];
        __hip_bfloat16 h = __float2bfloat16(v);
        size_t o = (size_t)(c0 + i) * R + r0 + tx;
        hiT[o] = h;
        if (loT) loT[o] = __float2bfloat16(v - __bfloat162float(h));
    }
}

// Vb[bh][t][d] -> Vt[bh][d][t]  (bf16 transpose, 64x64 tiles)
__global__ void vtrans_kernel(const ushort_t* __restrict__ Vb,
                              ushort_t* __restrict__ Vt) {
    __shared__ ushort_t tl[64][68];
    const int bh = blockIdx.x & 31, tt = blockIdx.x >> 5;
    const int tid = threadIdx.x;
    {
        const int t = tid >> 2, d0 = (tid & 3) * 16;
        const uint4 u = *(const uint4*)(Vb + ((size_t)bh * TSEQ + tt * 64 + t) * 64 + d0);
        *(uint4*)&tl[t][d0] = u;
        *(uint4*)&tl[t][d0 + 8] = *(const uint4*)(Vb + ((size_t)bh * TSEQ + tt * 64 + t) * 64 + d0 + 8);
    }
    __syncthreads();
    const int d = tid >> 2, t0 = (tid & 3) * 16;
    unsigned int wbuf[8];
    #pragma unroll
    for (int j = 0; j < 8; ++j)
        wbuf[j] = (unsigned int)tl[t0 + 2 * j][d] | ((unsigned int)tl[t0 + 2 * j + 1][d] << 16);
    ushort_t* dst = Vt + ((size_t)bh * 64 + d) * TSEQ + tt * 64 + t0;
    *(uint4*)dst       = make_uint4(wbuf[0], wbuf[1], wbuf[2], wbuf[3]);
    *(uint4*)(dst + 8) = make_uint4(wbuf[4], wbuf[5], wbuf[6], wbuf[7]);
}

// ---------------- LoRA rank-16 projection, 4-way K-split ----------------
__global__ void lora_t_part_kernel(const float* __restrict__ x,
                                   const float* __restrict__ la,
                                   float* __restrict__ tpart, int K) {
    __shared__ float Xs[16][64];
    const int tid = threadIdx.x;
    const int ty = tid >> 4, tx = tid & 15;
    const int row0 = blockIdx.x * 16;
    const int kbase = blockIdx.y * 256;
    float acc = 0.0f;
    for (int k0 = kbase; k0 < kbase + 256; k0 += 64) {
        int rr = tid >> 4, kk = (tid & 15) * 4;
        float4 v = *(const float4*)(x + (size_t)(row0 + rr) * K + k0 + kk);
        Xs[rr][kk] = v.x; Xs[rr][kk + 1] = v.y; Xs[rr][kk + 2] = v.z; Xs[rr][kk + 3] = v.w;
        __syncthreads();
        for (int k = 0; k < 64; ++k)
            acc += Xs[ty][k] * la[(size_t)(k0 + k) * RANK + tx];
        __syncthreads();
    }
    tpart[((size_t)blockIdx.y * M_TOTAL + row0 + ty) * RANK + tx] = acc;
}

__global__ void lora_t_part_bf16_kernel(const ushort_t* __restrict__ x,
                                        const float* __restrict__ la,
                                        float* __restrict__ tpart, int K) {
    __shared__ float Xs[16][64];
    const int tid = threadIdx.x;
    const int ty = tid >> 4, tx = tid & 15;
    const int row0 = blockIdx.x * 16;
    const int kbase = blockIdx.y * 256;
    float acc = 0.0f;
    for (int k0 = kbase; k0 < kbase + 256; k0 += 64) {
        int rr = tid >> 4, kk = (tid & 15) * 4;
        const ushort4 u = *(const ushort4*)(x + (size_t)(row0 + rr) * K + k0 + kk);
        Xs[rr][kk] = bfraw2f(u.x); Xs[rr][kk + 1] = bfraw2f(u.y);
        Xs[rr][kk + 2] = bfraw2f(u.z); Xs[rr][kk + 3] = bfraw2f(u.w);
        __syncthreads();
        for (int k = 0; k < 64; ++k)
            acc += Xs[ty][k] * la[(size_t)(k0 + k) * RANK + tx];
        __syncthreads();
    }
    tpart[((size_t)blockIdx.y * M_TOTAL + row0 + ty) * RANK + tx] = acc;
}

// ---------------- MFMA GEMM (128x128 tile, BK=32, 3 blocks/CU) ----------------
// XCD-aware block swizzle: consecutive blockIdx -> consecutive XCD (round-robin),
// so remap lid into 8 per-XCD sub-rectangles (2 col-groups x 4 row-groups) to
// keep each XCD's A-rows / W-cols resident in its private 4MB L2.
__device__ __forceinline__ int sw_off(int r, int c) {
    return ((r >> 1) << 7) + (((((r & 1) << 2) | c) ^ ((r >> 1) & 7)) << 4);
}

template <bool SPLIT>
__global__ __launch_bounds__(256, 3)
void gemm_mfma_kernel(const __hip_bfloat16* __restrict__ Ah,
                      const __hip_bfloat16* __restrict__ Al,
                      const __hip_bfloat16* __restrict__ Bh,
                      const __hip_bfloat16* __restrict__ Bl,
                      const float* __restrict__ bias,
                      const float* __restrict__ tpart,
                      const float* __restrict__ lb,
                      float* __restrict__ Cf,
                      ushort_t* __restrict__ Qb,
                      ushort_t* __restrict__ Kb,
                      ushort_t* __restrict__ Vb,
                      const float* __restrict__ sp,
                      const float* __restrict__ zp,
                      int M, int N, int K, int split_col0, int out_mode) {
    constexpr int TILE = 128 * 32;              // bf16 elements per 128x32 tile
    __shared__ __hip_bfloat16 As[(SPLIT ? 2 : 1) * TILE];
    __shared__ __hip_bfloat16 Bs[(SPLIT ? 2 : 1) * TILE];
    __shared__ float Ts[128 * 16];
    __shared__ float Ls[16 * 128];

    const int tid = threadIdx.x;
    const int lane = tid & 63, w = tid >> 6;

    // ---- XCD swizzle ----
    int bcol, brow;
    {
        const int NC = gridDim.x, NR = gridDim.y;
        const int lid = blockIdx.y * NC + blockIdx.x;
        const int xcd = lid & 7, s = lid >> 3;
        const int cw = NC >> 1, rh = NR >> 2;     // strip dims (NC even, NR%4==0)
        const int cg = xcd & 1, rg = xcd >> 1;
        bcol = cg * cw + (s % cw);
        brow = rg * rh + (s / cw);
    }
    const int row0 = brow * 128, col0 = bcol * 128;
    const int wr = (w >> 1) * 64, wc = (w & 1) * 64;
    const bool do_split = SPLIT && (col0 >= split_col0);

    const int s_lc = (lane & 7) ^ ((lane >> 3) & 7);
    const int s_rb = 2 * (lane >> 3) + (s_lc >> 2);
    const int s_c8 = (s_lc & 3) * 8;

    float qsc = 0.f, qzp = 0.f;
    if (out_mode == 1) { qsc = sp[0]; qzp = zp[0]; }

    f32x4 acc[4][4];
    #pragma unroll
    for (int i = 0; i < 4; ++i)
        #pragma unroll
        for (int j = 0; j < 4; ++j)
            acc[i][j] = (f32x4){0.f, 0.f, 0.f, 0.f};

    const int arow = wr + (lane & 15);
    const int chunk = lane >> 4;

    for (int k0 = 0; k0 < K; k0 += 32) {
        #pragma unroll
        for (int qq = 0; qq < 2; ++qq) {
            const int q = 2 * w + qq;          // 16-row group 0..7
            const int r = 16 * q + s_rb;
            const __hip_bfloat16* gA = Ah + (size_t)(row0 + r) * K + k0 + s_c8;
            __builtin_amdgcn_global_load_lds(
                (const __attribute__((address_space(1))) void*)gA,
                (__attribute__((address_space(3))) void*)(As + q * 512), 16, 0, 0);
            const __hip_bfloat16* gB = Bh + (size_t)(col0 + r) * K + k0 + s_c8;
            __builtin_amdgcn_global_load_lds(
                (const __attribute__((address_space(1))) void*)gB,
                (__attribute__((address_space(3))) void*)(Bs + q * 512), 16, 0, 0);
            if (do_split) {
                const __hip_bfloat16* gAl = Al + (size_t)(row0 + r) * K + k0 + s_c8;
                __builtin_amdgcn_global_load_lds(
                    (const __attribute__((address_space(1))) void*)gAl,
                    (__attribute__((address_space(3))) void*)(As + TILE + q * 512), 16, 0, 0);
                const __hip_bfloat16* gBl = Bl + (size_t)(col0 + r) * K + k0 + s_c8;
                __builtin_amdgcn_global_load_lds(
                    (const __attribute__((address_space(1))) void*)gBl,
                    (__attribute__((address_space(3))) void*)(Bs + TILE + q * 512), 16, 0, 0);
            }
        }
        __syncthreads();

        const char* ab = (const char*)As;
        const char* bb = (const char*)Bs;
        bf16x8 a_h[4], b_h[4], a_l[4], b_l[4];
        #pragma unroll
        for (int mi = 0; mi < 4; ++mi) {
            int off = sw_off(arow + mi * 16, chunk);
            a_h[mi] = *(const bf16x8*)(ab + off);
            if (do_split) a_l[mi] = *(const bf16x8*)(ab + 2 * TILE + off);
        }
        #pragma unroll
        for (int nj = 0; nj < 4; ++nj) {
            int off = sw_off(wc + nj * 16 + (lane & 15), chunk);
            b_h[nj] = *(const bf16x8*)(bb + off);
            if (do_split) b_l[nj] = *(const bf16x8*)(bb + 2 * TILE + off);
        }
        #pragma unroll
        for (int mi = 0; mi < 4; ++mi)
            #pragma unroll
            for (int nj = 0; nj < 4; ++nj) {
                acc[mi][nj] = __builtin_amdgcn_mfma_f32_16x16x32_bf16(a_h[mi], b_h[nj], acc[mi][nj], 0, 0, 0);
                if (do_split) {
                    acc[mi][nj] = __builtin_amdgcn_mfma_f32_16x16x32_bf16(a_h[mi], b_l[nj], acc[mi][nj], 0, 0, 0);
                    acc[mi][nj] = __builtin_amdgcn_mfma_f32_16x16x32_bf16(a_l[mi], b_h[nj], acc[mi][nj], 0, 0, 0);
                }
            }
        __syncthreads();
    }

    // ---- epilogue: bias + LORA_SCALE * ((sum of tparts) @ lb) ----
    {
        int r = tid >> 1, j0 = (tid & 1) * 8;
        float4 t0 = {0, 0, 0, 0}, t1 = {0, 0, 0, 0};
        #pragma unroll
        for (int c = 0; c < 4; ++c) {
            const float* src = tpart + ((size_t)c * M_TOTAL + row0 + r) * RANK + j0;
            float4 s0 = *(const float4*)src;
            float4 s1 = *(const float4*)(src + 4);
            t0.x += s0.x; t0.y += s0.y; t0.z += s0.z; t0.w += s0.w;
            t1.x += s1.x; t1.y += s1.y; t1.z += s1.z; t1.w += s1.w;
        }
        *(float4*)(Ts + r * 16 + j0)     = t0;
        *(float4*)(Ts + r * 16 + j0 + 4) = t1;
        int rr = tid >> 4, c0 = (tid & 15) * 8;
        const float4* lsrc = (const float4*)(lb + (size_t)rr * N + col0 + c0);
        float4* ldst = (float4*)(Ls + rr * 128 + c0);
        ldst[0] = lsrc[0]; ldst[1] = lsrc[1];
    }
    __syncthreads();
    #pragma unroll
    for (int mi = 0; mi < 4; ++mi)
        #pragma unroll
        for (int nj = 0; nj < 4; ++nj) {
            const int coll = wc + nj * 16 + (lane & 15);
            const float bv = bias[col0 + coll];
            #pragma unroll
            for (int rg = 0; rg < 4; ++rg) {
                const int rowl = wr + mi * 16 + (lane >> 4) * 4 + rg;
                float lsum = 0.f;
                #pragma unroll
                for (int rr = 0; rr < 16; ++rr)
                    lsum += Ts[rowl * 16 + rr] * Ls[rr * 128 + coll];
                const float val = acc[mi][nj][rg] + bv + LORA_SCALE * lsum;
                if (out_mode == 0) {
                    Cf[(size_t)(row0 + rowl) * N + col0 + coll] = val;
                } else {
                    const int R = row0 + rowl;
                    const int b = R >> 11, t = R & 2047;
                    const int CN = col0 + coll;
                    const int sec = CN >> 10, head = (CN >> 6) & 15, d = CN & 63;
                    const size_t off = (((size_t)(b * 16 + head)) * TSEQ + t) * 64 + d;
                    if (sec == 0)      Qb[off] = bf16bits(val * 0.125f);
                    else if (sec == 1) Kb[off] = bf16bits(fake_quant(val, qsc, qzp));
                    else               Vb[off] = bf16bits(fake_quant(val, qsc, qzp));
                }
            }
        }
}

// ---------------- MFMA flash attention (round-7 proven 64-row version) ----------------
__global__ __launch_bounds__(256)
void mfma_attn_kernel(const ushort_t* __restrict__ Qb,   // [bh][T][64] (x0.125)
                      const ushort_t* __restrict__ Kq,   // [bh][T][64]
                      const ushort_t* __restrict__ Vtq,  // [bh][64][T]
                      ushort_t* __restrict__ outb) {     // [B][T][1024] bf16
    const int bx = blockIdx.x;
    const int bh = bx & 31;
    const int qt = 31 - (bx >> 5);                 // heavy q-tiles dispatch first
    const int b = bh >> 4, h = bh & 15;
    const int tid = threadIdx.x;
    const int lane = tid & 63, w = tid >> 6;
    const int m16 = lane & 15, qc = lane >> 4;
    const int m7 = m16 & 7;

    __shared__ ushort_t Qs[4096];
    __shared__ ushort_t Ks[4096];
    __shared__ ushort_t Vs[4096];
    __shared__ ushort_t Ps[4096];

    const int s_g = (lane & 7) ^ ((lane >> 3) & 7);
    const int s_r = lane >> 3;

    const ushort_t* Qg = Qb + (size_t)bh * TSEQ * 64;
    const ushort_t* Kg = Kq + (size_t)bh * TSEQ * 64;
    const ushort_t* Vg = Vtq + (size_t)bh * 64 * TSEQ;

    #pragma unroll
    for (int pp = 0; pp < 2; ++pp) {
        const int p = 2 * w + pp;
        const ushort_t* gq = Qg + ((size_t)(qt * 64 + 8 * p + s_r)) * 64 + s_g * 8;
        __builtin_amdgcn_global_load_lds(
            (const __attribute__((address_space(1))) void*)gq,
            (__attribute__((address_space(3))) void*)(Qs + p * 512), 16, 0, 0);
    }
    __syncthreads();

    bf16x8 a_q[2];
    {
        const int row = 16 * w + m16;
        #pragma unroll
        for (int c = 0; c < 2; ++c) {
            const int g = qc + 4 * c;
            a_q[c] = *(const bf16x8*)((const char*)Qs + row * 128 + ((g ^ m7) << 4));
        }
    }

    float m_st[4], l_st[4];
    f32x4 o_acc[4];
    #pragma unroll
    for (int r = 0; r < 4; ++r) { m_st[r] = -INFINITY; l_st[r] = 0.0f; }
    #pragma unroll
    for (int dj = 0; dj < 4; ++dj) o_acc[dj] = (f32x4){0.f, 0.f, 0.f, 0.f};

    for (int kt = 0; kt <= qt; ++kt) {
        __syncthreads();
        #pragma unroll
        for (int pp = 0; pp < 2; ++pp) {
            const int p = 2 * w + pp;
            const ushort_t* gk = Kg + ((size_t)(kt * 64 + 8 * p + s_r)) * 64 + s_g * 8;
            __builtin_amdgcn_global_load_lds(
                (const __attribute__((address_space(1))) void*)gk,
                (__attribute__((address_space(3))) void*)(Ks + p * 512), 16, 0, 0);
            const ushort_t* gv = Vg + ((size_t)(8 * p + s_r)) * TSEQ + kt * 64 + s_g * 8;
            __builtin_amdgcn_global_load_lds(
                (const __attribute__((address_space(1))) void*)gv,
                (__attribute__((address_space(3))) void*)(Vs + p * 512), 16, 0, 0);
        }
        __syncthreads();

        const bool diag = (kt == qt);
        const int nj_hi = diag ? (w + 1) : 4;

        f32x4 s[4];
        #pragma unroll
        for (int nj = 0; nj < 4; ++nj) s[nj] = (f32x4){0.f, 0.f, 0.f, 0.f};
        #pragma unroll
        for (int c = 0; c < 2; ++c) {
            #pragma unroll
            for (int nj = 0; nj < 4; ++nj) {
                if (nj < nj_hi) {
                    const int row = 16 * nj + m16;
                    const int g = qc + 4 * c;
                    bf16x8 bk = *(const bf16x8*)((const char*)Ks + row * 128 + ((g ^ m7) << 4));
                    s[nj] = __builtin_amdgcn_mfma_f32_16x16x32_bf16(a_q[c], bk, s[nj], 0, 0, 0);
                }
            }
        }

        float alpha[4], p_[4][4];
        #pragma unroll
        for (int reg = 0; reg < 4; ++reg) {
            const int qrow = 16 * w + 4 * qc + reg;
            float sv[4];
            float rm = -INFINITY;
            #pragma unroll
            for (int nj = 0; nj < 4; ++nj) {
                float v = s[nj][reg];
                if (diag && (m16 + 16 * nj > qrow)) v = -INFINITY;
                sv[nj] = v;
                rm = fmaxf(rm, v);
            }
            #pragma unroll
            for (int off = 1; off < 16; off <<= 1)
                rm = fmaxf(rm, __shfl_xor(rm, off, 16));
            const float mo = m_st[reg];
            const float mn = fmaxf(mo, rm);
            const float al = __expf(mo - mn);
            float rs = 0.f;
            #pragma unroll
            for (int nj = 0; nj < 4; ++nj) {
                float pv = __expf(sv[nj] - mn);
                p_[reg][nj] = pv;
                rs += pv;
            }
            #pragma unroll
            for (int off = 1; off < 16; off <<= 1)
                rs += __shfl_xor(rs, off, 16);
            l_st[reg] = al * l_st[reg] + rs;
            m_st[reg] = mn;
            alpha[reg] = al;
        }

        #pragma unroll
        for (int reg = 0; reg < 4; ++reg) {
            const int row = 16 * w + 4 * qc + reg;
            const int r7 = row & 7;
            #pragma unroll
            for (int nj = 0; nj < 4; ++nj) {
                const int k = m16 + 16 * nj;
                Ps[row * 64 + (((k >> 3) ^ r7) << 3) + (k & 7)] = bf16bits(p_[reg][nj]);
            }
        }

        #pragma unroll
        for (int dj = 0; dj < 4; ++dj)
            #pragma unroll
            for (int reg = 0; reg < 4; ++reg)
                o_acc[dj][reg] *= alpha[reg];

        const int c_hi = diag ? (w >= 2 ? 2 : 1) : 2;
        #pragma unroll
        for (int c = 0; c < 2; ++c) {
            if (c < c_hi) {
                const int rowp = 16 * w + m16;
                const int g = qc + 4 * c;
                bf16x8 ap = *(const bf16x8*)((const char*)Ps + rowp * 128 + ((g ^ m7) << 4));
                #pragma unroll
                for (int dj = 0; dj < 4; ++dj) {
                    const int rowv = 16 * dj + m16;
                    bf16x8 bv = *(const bf16x8*)((const char*)Vs + rowv * 128 + ((g ^ m7) << 4));
                    o_acc[dj] = __builtin_amdgcn_mfma_f32_16x16x32_bf16(ap, bv, o_acc[dj], 0, 0, 0);
                }
            }
        }
    }

    #pragma unroll
    for (int reg = 0; reg < 4; ++reg) {
        const float inv = 1.0f / l_st[reg];
        const int q = qt * 64 + 16 * w + 4 * qc + reg;
        #pragma unroll
        for (int dj = 0; dj < 4; ++dj) {
            const int d = m16 + 16 * dj;
            outb[((size_t)b * TSEQ + q) * N_EMBD + h * 64 + d] = bf16bits(o_acc[dj][reg] * inv);
        }
    }
}

extern "C" void kernel_launch(void* const* d_in, const int* in_sizes, int n_in,
                              void* d_out, int out_size, void* d_ws, size_t ws_size,
                              hipStream_t stream) {
    const float* x        = (const float*)d_in[0];
    const float* w_attn   = (const float*)d_in[1];
    const float* b_attn   = (const float*)d_in[2];
    const float* la_attn  = (const float*)d_in[3];
    const float* lb_attn  = (const float*)d_in[4];
    const float* w_proj   = (const float*)d_in[5];
    const float* b_proj   = (const float*)d_in[6];
    const float* la_proj  = (const float*)d_in[7];
    const float* lb_proj  = (const float*)d_in[8];
    const float* kv_scale = (const float*)d_in[9];
    const float* kv_zp    = (const float*)d_in[10];
    float* out = (float*)d_out;

    char* ws = (char*)d_ws;
    float* t_attn_p       = (float*)ws;          ws += (size_t)4 * M_TOTAL * RANK * 4;
    float* t_proj_p       = (float*)ws;          ws += (size_t)4 * M_TOTAL * RANK * 4;
    ushort_t* aob         = (ushort_t*)ws;       ws += (size_t)M_TOTAL * N_EMBD * 2;
    __hip_bfloat16* x_hi  = (__hip_bfloat16*)ws; ws += (size_t)M_TOTAL * N_EMBD * 2;
    __hip_bfloat16* x_lo  = (__hip_bfloat16*)ws; ws += (size_t)M_TOTAL * N_EMBD * 2;
    __hip_bfloat16* wqT_h = (__hip_bfloat16*)ws; ws += (size_t)C3 * N_EMBD * 2;
    __hip_bfloat16* wqT_l = (__hip_bfloat16*)ws; ws += (size_t)C3 * N_EMBD * 2;
    __hip_bfloat16* wpT   = (__hip_bfloat16*)ws; ws += (size_t)N_EMBD * N_EMBD * 2;
    ushort_t* Qb          = (ushort_t*)ws;       ws += (size_t)32 * TSEQ * 64 * 2;
    ushort_t* Kb          = (ushort_t*)ws;       ws += (size_t)32 * TSEQ * 64 * 2;
    ushort_t* Vb          = (ushort_t*)ws;       ws += (size_t)32 * TSEQ * 64 * 2;
    ushort_t* Vtq         = (ushort_t*)ws;       ws += (size_t)32 * 64 * TSEQ * 2;

    cvt_split_kernel<<<dim3(M_TOTAL * N_EMBD / 4 / 256), 256, 0, stream>>>(
        x, x_hi, x_lo, M_TOTAL * N_EMBD / 4);
    transpose_split_kernel<<<dim3(C3 / 32, N_EMBD / 32), 256, 0, stream>>>(
        w_attn, wqT_h, wqT_l, N_EMBD, C3);
    transpose_split_kernel<<<dim3(N_EMBD / 32, N_EMBD / 32), 256, 0, stream>>>(
        w_proj, wpT, nullptr, N_EMBD, N_EMBD);
    lora_t_part_kernel<<<dim3(M_TOTAL / 16, 4), 256, 0, stream>>>(x, la_attn, t_attn_p, N_EMBD);

    // split only V columns (col0 >= 2048) — round-5-validated numerics.
    gemm_mfma_kernel<true><<<dim3(C3 / 128, M_TOTAL / 128), 256, 0, stream>>>(
        x_hi, x_lo, wqT_h, wqT_l, b_attn, t_attn_p, lb_attn,
        nullptr, Qb, Kb, Vb, kv_scale, kv_zp,
        M_TOTAL, C3, N_EMBD, 2 * N_EMBD, 1);

    vtrans_kernel<<<dim3(32 * (TSEQ / 64)), 256, 0, stream>>>(Vb, Vtq);

    mfma_attn_kernel<<<dim3(32 * 32), 256, 0, stream>>>(Qb, Kb, Vtq, aob);

    lora_t_part_bf16_kernel<<<dim3(M_TOTAL / 16, 4), 256, 0, stream>>>(aob, la_proj, t_proj_p, N_EMBD);

    gemm_mfma_kernel<false><<<dim3(N_EMBD / 128, M_TOTAL / 128), 256, 0, stream>>>(
        (const __hip_bfloat16*)aob, nullptr, wpT, nullptr, b_proj, t_proj_p, lb_proj,
        out, nullptr, nullptr, nullptr, nullptr, nullptr,
        M_TOTAL, N_EMBD, N_EMBD, 1 << 30, 0);
}

// Round 10
// 345.720 us; speedup vs baseline: 1.1043x; 1.0052x over previous
//
#include <hip/hip_runtime.h>
#include <hip/hip_bf16.h>
#include <math.h>

#define N_EMBD   1024
#define N_HEAD   16
#define HEAD_DIM 64
#define BATCH    2
#define TSEQ     2048
#define RANK     16
#define LORA_SCALE 2.0f
#define M_TOTAL  (BATCH * TSEQ)   // 4096
#define C3       (3 * N_EMBD)     // 3072

typedef unsigned short ushort_t;
typedef __attribute__((ext_vector_type(8))) short bf16x8;
typedef __attribute__((ext_vector_type(4))) float f32x4;

__device__ __forceinline__ float fake_quant(float x, float scale, float zp) {
    float q = rintf(x / scale + zp);
    q = fminf(fmaxf(q, 0.0f), 255.0f);
    return (q - zp) * scale;
}

__device__ __forceinline__ ushort_t bf16bits(float f) {
    union { __hip_bfloat16 h; ushort_t u; } c;
    c.h = __float2bfloat16(f);
    return c.u;
}

__device__ __forceinline__ float bfraw2f(ushort_t u) {
    union { unsigned int i; float f; } c; c.i = ((unsigned int)u) << 16; return c.f;
}

// ---------------- conversion kernels ----------------
__global__ void cvt_split_kernel(const float* __restrict__ in,
                                 __hip_bfloat16* __restrict__ hi,
                                 __hip_bfloat16* __restrict__ lo, int n4) {
    int i = blockIdx.x * 256 + threadIdx.x;
    if (i >= n4) return;
    float4 v = ((const float4*)in)[i];
    float vs[4] = {v.x, v.y, v.z, v.w};
    #pragma unroll
    for (int k = 0; k < 4; ++k) {
        __hip_bfloat16 h = __float2bfloat16(vs[k]);
        hi[i * 4 + k] = h;
        lo[i * 4 + k] = __float2bfloat16(vs[k] - __bfloat162float(h));
    }
}

__global__ void transpose_split_kernel(const float* __restrict__ in,
                                       __hip_bfloat16* __restrict__ hiT,
                                       __hip_bfloat16* __restrict__ loT,
                                       int R, int C) {
    __shared__ float tl[32][33];
    const int c0 = blockIdx.x * 32, r0 = blockIdx.y * 32;
    const int tx = threadIdx.x & 31, ty = threadIdx.x >> 5;
    for (int i = ty; i < 32; i += 8)
        tl[i][tx] = in[(size_t)(r0 + i) * C + c0 + tx];
    __syncthreads();
    for (int i = ty; i < 32; i += 8) {
        float v = tl[tx][i];
        __hip_bfloat16 h = __float2bfloat16(v);
        size_t o = (size_t)(c0 + i) * R + r0 + tx;
        hiT[o] = h;
        if (loT) loT[o] = __float2bfloat16(v - __bfloat162float(h));
    }
}

// Vb[bh][t][d] -> Vt[bh][d][t]  (bf16 transpose, 64x64 tiles)
__global__ void vtrans_kernel(const ushort_t* __restrict__ Vb,
                              ushort_t* __restrict__ Vt) {
    __shared__ ushort_t tl[64][68];
    const int bh = blockIdx.x & 31, tt = blockIdx.x >> 5;
    const int tid = threadIdx.x;
    {
        const int t = tid >> 2, d0 = (tid & 3) * 16;
        const uint4 u = *(const uint4*)(Vb + ((size_t)bh * TSEQ + tt * 64 + t) * 64 + d0);
        *(uint4*)&tl[t][d0] = u;
        *(uint4*)&tl[t][d0 + 8] = *(const uint4*)(Vb + ((size_t)bh * TSEQ + tt * 64 + t) * 64 + d0 + 8);
    }
    __syncthreads();
    const int d = tid >> 2, t0 = (tid & 3) * 16;
    unsigned int wbuf[8];
    #pragma unroll
    for (int j = 0; j < 8; ++j)
        wbuf[j] = (unsigned int)tl[t0 + 2 * j][d] | ((unsigned int)tl[t0 + 2 * j + 1][d] << 16);
    ushort_t* dst = Vt + ((size_t)bh * 64 + d) * TSEQ + tt * 64 + t0;
    *(uint4*)dst       = make_uint4(wbuf[0], wbuf[1], wbuf[2], wbuf[3]);
    *(uint4*)(dst + 8) = make_uint4(wbuf[4], wbuf[5], wbuf[6], wbuf[7]);
}

// ---------------- LoRA rank-16 projection, 4-way K-split ----------------
__global__ void lora_t_part_kernel(const float* __restrict__ x,
                                   const float* __restrict__ la,
                                   float* __restrict__ tpart, int K) {
    __shared__ float Xs[16][64];
    const int tid = threadIdx.x;
    const int ty = tid >> 4, tx = tid & 15;
    const int row0 = blockIdx.x * 16;
    const int kbase = blockIdx.y * 256;
    float acc = 0.0f;
    for (int k0 = kbase; k0 < kbase + 256; k0 += 64) {
        int rr = tid >> 4, kk = (tid & 15) * 4;
        float4 v = *(const float4*)(x + (size_t)(row0 + rr) * K + k0 + kk);
        Xs[rr][kk] = v.x; Xs[rr][kk + 1] = v.y; Xs[rr][kk + 2] = v.z; Xs[rr][kk + 3] = v.w;
        __syncthreads();
        for (int k = 0; k < 64; ++k)
            acc += Xs[ty][k] * la[(size_t)(k0 + k) * RANK + tx];
        __syncthreads();
    }
    tpart[((size_t)blockIdx.y * M_TOTAL + row0 + ty) * RANK + tx] = acc;
}

__global__ void lora_t_part_bf16_kernel(const ushort_t* __restrict__ x,
                                        const float* __restrict__ la,
                                        float* __restrict__ tpart, int K) {
    __shared__ float Xs[16][64];
    const int tid = threadIdx.x;
    const int ty = tid >> 4, tx = tid & 15;
    const int row0 = blockIdx.x * 16;
    const int kbase = blockIdx.y * 256;
    float acc = 0.0f;
    for (int k0 = kbase; k0 < kbase + 256; k0 += 64) {
        int rr = tid >> 4, kk = (tid & 15) * 4;
        const ushort4 u = *(const ushort4*)(x + (size_t)(row0 + rr) * K + k0 + kk);
        Xs[rr][kk] = bfraw2f(u.x); Xs[rr][kk + 1] = bfraw2f(u.y);
        Xs[rr][kk + 2] = bfraw2f(u.z); Xs[rr][kk + 3] = bfraw2f(u.w);
        __syncthreads();
        for (int k = 0; k < 64; ++k)
            acc += Xs[ty][k] * la[(size_t)(k0 + k) * RANK + tx];
        __syncthreads();
    }
    tpart[((size_t)blockIdx.y * M_TOTAL + row0 + ty) * RANK + tx] = acc;
}

// ---------------- MFMA GEMM (128x128 tile, BK=32, 3 blocks/CU) ----------------
// XCD-aware block swizzle + phase-staggered K-loop: block lid starts its K
// iteration at ((lid*7)&31) and wraps — desynchronizes the per-iteration
// staging bursts across co-resident blocks (accumulation is K-order-free).
__device__ __forceinline__ int sw_off(int r, int c) {
    return ((r >> 1) << 7) + (((((r & 1) << 2) | c) ^ ((r >> 1) & 7)) << 4);
}

template <bool SPLIT>
__global__ __launch_bounds__(256, 3)
void gemm_mfma_kernel(const __hip_bfloat16* __restrict__ Ah,
                      const __hip_bfloat16* __restrict__ Al,
                      const __hip_bfloat16* __restrict__ Bh,
                      const __hip_bfloat16* __restrict__ Bl,
                      const float* __restrict__ bias,
                      const float* __restrict__ tpart,
                      const float* __restrict__ lb,
                      float* __restrict__ Cf,
                      ushort_t* __restrict__ Qb,
                      ushort_t* __restrict__ Kb,
                      ushort_t* __restrict__ Vb,
                      const float* __restrict__ sp,
                      const float* __restrict__ zp,
                      int M, int N, int K, int split_col0, int out_mode) {
    constexpr int TILE = 128 * 32;              // bf16 elements per 128x32 tile
    __shared__ __hip_bfloat16 As[(SPLIT ? 2 : 1) * TILE];
    __shared__ __hip_bfloat16 Bs[(SPLIT ? 2 : 1) * TILE];
    __shared__ float Ts[128 * 16];
    __shared__ float Ls[16 * 128];

    const int tid = threadIdx.x;
    const int lane = tid & 63, w = tid >> 6;

    // ---- XCD swizzle ----
    int bcol, brow, phase;
    {
        const int NC = gridDim.x, NR = gridDim.y;
        const int lid = blockIdx.y * NC + blockIdx.x;
        const int xcd = lid & 7, s = lid >> 3;
        const int cw = NC >> 1, rh = NR >> 2;     // strip dims (NC even, NR%4==0)
        const int cg = xcd & 1, rg = xcd >> 1;
        bcol = cg * cw + (s % cw);
        brow = rg * rh + (s / cw);
        phase = (lid * 7) & 31;                   // K-loop stagger
    }
    const int row0 = brow * 128, col0 = bcol * 128;
    const int wr = (w >> 1) * 64, wc = (w & 1) * 64;
    const bool do_split = SPLIT && (col0 >= split_col0);

    const int s_lc = (lane & 7) ^ ((lane >> 3) & 7);
    const int s_rb = 2 * (lane >> 3) + (s_lc >> 2);
    const int s_c8 = (s_lc & 3) * 8;

    float qsc = 0.f, qzp = 0.f;
    if (out_mode == 1) { qsc = sp[0]; qzp = zp[0]; }

    f32x4 acc[4][4];
    #pragma unroll
    for (int i = 0; i < 4; ++i)
        #pragma unroll
        for (int j = 0; j < 4; ++j)
            acc[i][j] = (f32x4){0.f, 0.f, 0.f, 0.f};

    const int arow = wr + (lane & 15);
    const int chunk = lane >> 4;

    const int KI = K >> 5;                       // K iterations (32 for K=1024)
    for (int kk = 0; kk < KI; ++kk) {
        const int k0 = (((kk + phase) & (KI - 1)) << 5);
        #pragma unroll
        for (int qq = 0; qq < 2; ++qq) {
            const int q = 2 * w + qq;          // 16-row group 0..7
            const int r = 16 * q + s_rb;
            const __hip_bfloat16* gA = Ah + (size_t)(row0 + r) * K + k0 + s_c8;
            __builtin_amdgcn_global_load_lds(
                (const __attribute__((address_space(1))) void*)gA,
                (__attribute__((address_space(3))) void*)(As + q * 512), 16, 0, 0);
            const __hip_bfloat16* gB = Bh + (size_t)(col0 + r) * K + k0 + s_c8;
            __builtin_amdgcn_global_load_lds(
                (const __attribute__((address_space(1))) void*)gB,
                (__attribute__((address_space(3))) void*)(Bs + q * 512), 16, 0, 0);
            if (do_split) {
                const __hip_bfloat16* gAl = Al + (size_t)(row0 + r) * K + k0 + s_c8;
                __builtin_amdgcn_global_load_lds(
                    (const __attribute__((address_space(1))) void*)gAl,
                    (__attribute__((address_space(3))) void*)(As + TILE + q * 512), 16, 0, 0);
                const __hip_bfloat16* gBl = Bl + (size_t)(col0 + r) * K + k0 + s_c8;
                __builtin_amdgcn_global_load_lds(
                    (const __attribute__((address_space(1))) void*)gBl,
                    (__attribute__((address_space(3))) void*)(Bs + TILE + q * 512), 16, 0, 0);
            }
        }
        __syncthreads();

        const char* ab = (const char*)As;
        const char* bb = (const char*)Bs;
        bf16x8 a_h[4], b_h[4], a_l[4], b_l[4];
        #pragma unroll
        for (int mi = 0; mi < 4; ++mi) {
            int off = sw_off(arow + mi * 16, chunk);
            a_h[mi] = *(const bf16x8*)(ab + off);
            if (do_split) a_l[mi] = *(const bf16x8*)(ab + 2 * TILE + off);
        }
        #pragma unroll
        for (int nj = 0; nj < 4; ++nj) {
            int off = sw_off(wc + nj * 16 + (lane & 15), chunk);
            b_h[nj] = *(const bf16x8*)(bb + off);
            if (do_split) b_l[nj] = *(const bf16x8*)(bb + 2 * TILE + off);
        }
        #pragma unroll
        for (int mi = 0; mi < 4; ++mi)
            #pragma unroll
            for (int nj = 0; nj < 4; ++nj) {
                acc[mi][nj] = __builtin_amdgcn_mfma_f32_16x16x32_bf16(a_h[mi], b_h[nj], acc[mi][nj], 0, 0, 0);
                if (do_split) {
                    acc[mi][nj] = __builtin_amdgcn_mfma_f32_16x16x32_bf16(a_h[mi], b_l[nj], acc[mi][nj], 0, 0, 0);
                    acc[mi][nj] = __builtin_amdgcn_mfma_f32_16x16x32_bf16(a_l[mi], b_h[nj], acc[mi][nj], 0, 0, 0);
                }
            }
        __syncthreads();
    }

    // ---- epilogue: bias + LORA_SCALE * ((sum of tparts) @ lb) ----
    {
        int r = tid >> 1, j0 = (tid & 1) * 8;
        float4 t0 = {0, 0, 0, 0}, t1 = {0, 0, 0, 0};
        #pragma unroll
        for (int c = 0; c < 4; ++c) {
            const float* src = tpart + ((size_t)c * M_TOTAL + row0 + r) * RANK + j0;
            float4 s0 = *(const float4*)src;
            float4 s1 = *(const float4*)(src + 4);
            t0.x += s0.x; t0.y += s0.y; t0.z += s0.z; t0.w += s0.w;
            t1.x += s1.x; t1.y += s1.y; t1.z += s1.z; t1.w += s1.w;
        }
        *(float4*)(Ts + r * 16 + j0)     = t0;
        *(float4*)(Ts + r * 16 + j0 + 4) = t1;
        int rr = tid >> 4, c0 = (tid & 15) * 8;
        const float4* lsrc = (const float4*)(lb + (size_t)rr * N + col0 + c0);
        float4* ldst = (float4*)(Ls + rr * 128 + c0);
        ldst[0] = lsrc[0]; ldst[1] = lsrc[1];
    }
    __syncthreads();
    #pragma unroll
    for (int mi = 0; mi < 4; ++mi)
        #pragma unroll
        for (int nj = 0; nj < 4; ++nj) {
            const int coll = wc + nj * 16 + (lane & 15);
            const float bv = bias[col0 + coll];
            #pragma unroll
            for (int rg = 0; rg < 4; ++rg) {
                const int rowl = wr + mi * 16 + (lane >> 4) * 4 + rg;
                float lsum = 0.f;
                #pragma unroll
                for (int rr = 0; rr < 16; ++rr)
                    lsum += Ts[rowl * 16 + rr] * Ls[rr * 128 + coll];
                const float val = acc[mi][nj][rg] + bv + LORA_SCALE * lsum;
                if (out_mode == 0) {
                    Cf[(size_t)(row0 + rowl) * N + col0 + coll] = val;
                } else {
                    const int R = row0 + rowl;
                    const int b = R >> 11, t = R & 2047;
                    const int CN = col0 + coll;
                    const int sec = CN >> 10, head = (CN >> 6) & 15, d = CN & 63;
                    const size_t off = (((size_t)(b * 16 + head)) * TSEQ + t) * 64 + d;
                    if (sec == 0)      Qb[off] = bf16bits(val * 0.125f);
                    else if (sec == 1) Kb[off] = bf16bits(fake_quant(val, qsc, qzp));
                    else               Vb[off] = bf16bits(fake_quant(val, qsc, qzp));
                }
            }
        }
}

// ---------------- MFMA flash attention (round-7 proven 64-row version) ----------------
__global__ __launch_bounds__(256)
void mfma_attn_kernel(const ushort_t* __restrict__ Qb,   // [bh][T][64] (x0.125)
                      const ushort_t* __restrict__ Kq,   // [bh][T][64]
                      const ushort_t* __restrict__ Vtq,  // [bh][64][T]
                      ushort_t* __restrict__ outb) {     // [B][T][1024] bf16
    const int bx = blockIdx.x;
    const int bh = bx & 31;
    const int qt = 31 - (bx >> 5);                 // heavy q-tiles dispatch first
    const int b = bh >> 4, h = bh & 15;
    const int tid = threadIdx.x;
    const int lane = tid & 63, w = tid >> 6;
    const int m16 = lane & 15, qc = lane >> 4;
    const int m7 = m16 & 7;

    __shared__ ushort_t Qs[4096];
    __shared__ ushort_t Ks[4096];
    __shared__ ushort_t Vs[4096];
    __shared__ ushort_t Ps[4096];

    const int s_g = (lane & 7) ^ ((lane >> 3) & 7);
    const int s_r = lane >> 3;

    const ushort_t* Qg = Qb + (size_t)bh * TSEQ * 64;
    const ushort_t* Kg = Kq + (size_t)bh * TSEQ * 64;
    const ushort_t* Vg = Vtq + (size_t)bh * 64 * TSEQ;

    #pragma unroll
    for (int pp = 0; pp < 2; ++pp) {
        const int p = 2 * w + pp;
        const ushort_t* gq = Qg + ((size_t)(qt * 64 + 8 * p + s_r)) * 64 + s_g * 8;
        __builtin_amdgcn_global_load_lds(
            (const __attribute__((address_space(1))) void*)gq,
            (__attribute__((address_space(3))) void*)(Qs + p * 512), 16, 0, 0);
    }
    __syncthreads();

    bf16x8 a_q[2];
    {
        const int row = 16 * w + m16;
        #pragma unroll
        for (int c = 0; c < 2; ++c) {
            const int g = qc + 4 * c;
            a_q[c] = *(const bf16x8*)((const char*)Qs + row * 128 + ((g ^ m7) << 4));
        }
    }

    float m_st[4], l_st[4];
    f32x4 o_acc[4];
    #pragma unroll
    for (int r = 0; r < 4; ++r) { m_st[r] = -INFINITY; l_st[r] = 0.0f; }
    #pragma unroll
    for (int dj = 0; dj < 4; ++dj) o_acc[dj] = (f32x4){0.f, 0.f, 0.f, 0.f};

    for (int kt = 0; kt <= qt; ++kt) {
        __syncthreads();
        #pragma unroll
        for (int pp = 0; pp < 2; ++pp) {
            const int p = 2 * w + pp;
            const ushort_t* gk = Kg + ((size_t)(kt * 64 + 8 * p + s_r)) * 64 + s_g * 8;
            __builtin_amdgcn_global_load_lds(
                (const __attribute__((address_space(1))) void*)gk,
                (__attribute__((address_space(3))) void*)(Ks + p * 512), 16, 0, 0);
            const ushort_t* gv = Vg + ((size_t)(8 * p + s_r)) * TSEQ + kt * 64 + s_g * 8;
            __builtin_amdgcn_global_load_lds(
                (const __attribute__((address_space(1))) void*)gv,
                (__attribute__((address_space(3))) void*)(Vs + p * 512), 16, 0, 0);
        }
        __syncthreads();

        const bool diag = (kt == qt);
        const int nj_hi = diag ? (w + 1) : 4;

        f32x4 s[4];
        #pragma unroll
        for (int nj = 0; nj < 4; ++nj) s[nj] = (f32x4){0.f, 0.f, 0.f, 0.f};
        #pragma unroll
        for (int c = 0; c < 2; ++c) {
            #pragma unroll
            for (int nj = 0; nj < 4; ++nj) {
                if (nj < nj_hi) {
                    const int row = 16 * nj + m16;
                    const int g = qc + 4 * c;
                    bf16x8 bk = *(const bf16x8*)((const char*)Ks + row * 128 + ((g ^ m7) << 4));
                    s[nj] = __builtin_amdgcn_mfma_f32_16x16x32_bf16(a_q[c], bk, s[nj], 0, 0, 0);
                }
            }
        }

        float alpha[4], p_[4][4];
        #pragma unroll
        for (int reg = 0; reg < 4; ++reg) {
            const int qrow = 16 * w + 4 * qc + reg;
            float sv[4];
            float rm = -INFINITY;
            #pragma unroll
            for (int nj = 0; nj < 4; ++nj) {
                float v = s[nj][reg];
                if (diag && (m16 + 16 * nj > qrow)) v = -INFINITY;
                sv[nj] = v;
                rm = fmaxf(rm, v);
            }
            #pragma unroll
            for (int off = 1; off < 16; off <<= 1)
                rm = fmaxf(rm, __shfl_xor(rm, off, 16));
            const float mo = m_st[reg];
            const float mn = fmaxf(mo, rm);
            const float al = __expf(mo - mn);
            float rs = 0.f;
            #pragma unroll
            for (int nj = 0; nj < 4; ++nj) {
                float pv = __expf(sv[nj] - mn);
                p_[reg][nj] = pv;
                rs += pv;
            }
            #pragma unroll
            for (int off = 1; off < 16; off <<= 1)
                rs += __shfl_xor(rs, off, 16);
            l_st[reg] = al * l_st[reg] + rs;
            m_st[reg] = mn;
            alpha[reg] = al;
        }

        #pragma unroll
        for (int reg = 0; reg < 4; ++reg) {
            const int row = 16 * w + 4 * qc + reg;
            const int r7 = row & 7;
            #pragma unroll
            for (int nj = 0; nj < 4; ++nj) {
                const int k = m16 + 16 * nj;
                Ps[row * 64 + (((k >> 3) ^ r7) << 3) + (k & 7)] = bf16bits(p_[reg][nj]);
            }
        }

        #pragma unroll
        for (int dj = 0; dj < 4; ++dj)
            #pragma unroll
            for (int reg = 0; reg < 4; ++reg)
                o_acc[dj][reg] *= alpha[reg];

        const int c_hi = diag ? (w >= 2 ? 2 : 1) : 2;
        #pragma unroll
        for (int c = 0; c < 2; ++c) {
            if (c < c_hi) {
                const int rowp = 16 * w + m16;
                const int g = qc + 4 * c;
                bf16x8 ap = *(const bf16x8*)((const char*)Ps + rowp * 128 + ((g ^ m7) << 4));
                #pragma unroll
                for (int dj = 0; dj < 4; ++dj) {
                    const int rowv = 16 * dj + m16;
                    bf16x8 bv = *(const bf16x8*)((const char*)Vs + rowv * 128 + ((g ^ m7) << 4));
                    o_acc[dj] = __builtin_amdgcn_mfma_f32_16x16x32_bf16(ap, bv, o_acc[dj], 0, 0, 0);
                }
            }
        }
    }

    #pragma unroll
    for (int reg = 0; reg < 4; ++reg) {
        const float inv = 1.0f / l_st[reg];
        const int q = qt * 64 + 16 * w + 4 * qc + reg;
        #pragma unroll
        for (int dj = 0; dj < 4; ++dj) {
            const int d = m16 + 16 * dj;
            outb[((size_t)b * TSEQ + q) * N_EMBD + h * 64 + d] = bf16bits(o_acc[dj][reg] * inv);
        }
    }
}

extern "C" void kernel_launch(void* const* d_in, const int* in_sizes, int n_in,
                              void* d_out, int out_size, void* d_ws, size_t ws_size,
                              hipStream_t stream) {
    const float* x        = (const float*)d_in[0];
    const float* w_attn   = (const float*)d_in[1];
    const float* b_attn   = (const float*)d_in[2];
    const float* la_attn  = (const float*)d_in[3];
    const float* lb_attn  = (const float*)d_in[4];
    const float* w_proj   = (const float*)d_in[5];
    const float* b_proj   = (const float*)d_in[6];
    const float* la_proj  = (const float*)d_in[7];
    const float* lb_proj  = (const float*)d_in[8];
    const float* kv_scale = (const float*)d_in[9];
    const float* kv_zp    = (const float*)d_in[10];
    float* out = (float*)d_out;

    char* ws = (char*)d_ws;
    float* t_attn_p       = (float*)ws;          ws += (size_t)4 * M_TOTAL * RANK * 4;
    float* t_proj_p       = (float*)ws;          ws += (size_t)4 * M_TOTAL * RANK * 4;
    ushort_t* aob         = (ushort_t*)ws;       ws += (size_t)M_TOTAL * N_EMBD * 2;
    __hip_bfloat16* x_hi  = (__hip_bfloat16*)ws; ws += (size_t)M_TOTAL * N_EMBD * 2;
    __hip_bfloat16* x_lo  = (__hip_bfloat16*)ws; ws += (size_t)M_TOTAL * N_EMBD * 2;
    __hip_bfloat16* wqT_h = (__hip_bfloat16*)ws; ws += (size_t)C3 * N_EMBD * 2;
    __hip_bfloat16* wqT_l = (__hip_bfloat16*)ws; ws += (size_t)C3 * N_EMBD * 2;
    __hip_bfloat16* wpT   = (__hip_bfloat16*)ws; ws += (size_t)N_EMBD * N_EMBD * 2;
    ushort_t* Qb          = (ushort_t*)ws;       ws += (size_t)32 * TSEQ * 64 * 2;
    ushort_t* Kb          = (ushort_t*)ws;       ws += (size_t)32 * TSEQ * 64 * 2;
    ushort_t* Vb          = (ushort_t*)ws;       ws += (size_t)32 * TSEQ * 64 * 2;
    ushort_t* Vtq         = (ushort_t*)ws;       ws += (size_t)32 * 64 * TSEQ * 2;

    cvt_split_kernel<<<dim3(M_TOTAL * N_EMBD / 4 / 256), 256, 0, stream>>>(
        x, x_hi, x_lo, M_TOTAL * N_EMBD / 4);
    transpose_split_kernel<<<dim3(C3 / 32, N_EMBD / 32), 256, 0, stream>>>(
        w_attn, wqT_h, wqT_l, N_EMBD, C3);
    transpose_split_kernel<<<dim3(N_EMBD / 32, N_EMBD / 32), 256, 0, stream>>>(
        w_proj, wpT, nullptr, N_EMBD, N_EMBD);
    lora_t_part_kernel<<<dim3(M_TOTAL / 16, 4), 256, 0, stream>>>(x, la_attn, t_attn_p, N_EMBD);

    // split only V columns (col0 >= 2048) — round-5-validated numerics.
    gemm_mfma_kernel<true><<<dim3(C3 / 128, M_TOTAL / 128), 256, 0, stream>>>(
        x_hi, x_lo, wqT_h, wqT_l, b_attn, t_attn_p, lb_attn,
        nullptr, Qb, Kb, Vb, kv_scale, kv_zp,
        M_TOTAL, C3, N_EMBD, 2 * N_EMBD, 1);

    vtrans_kernel<<<dim3(32 * (TSEQ / 64)), 256, 0, stream>>>(Vb, Vtq);

    mfma_attn_kernel<<<dim3(32 * 32), 256, 0, stream>>>(Qb, Kb, Vtq, aob);

    lora_t_part_bf16_kernel<<<dim3(M_TOTAL / 16, 4), 256, 0, stream>>>(aob, la_proj, t_proj_p, N_EMBD);

    gemm_mfma_kernel<false><<<dim3(N_EMBD / 128, M_TOTAL / 128), 256, 0, stream>>>(
        (const __hip_bfloat16*)aob, nullptr, wpT, nullptr, b_proj, t_proj_p, lb_proj,
        out, nullptr, nullptr, nullptr, nullptr, nullptr,
        M_TOTAL, N_EMBD, N_EMBD, 1 << 30, 0);
}